// Round 4
// baseline (3085.131 us; speedup 1.0000x reference)
//
#include <hip/hip_runtime.h>
#include <math.h>
#include <float.h>
#include <limits.h>

// Problem constants
#define PIX     13824   // 64*216
#define QPIX    3456    // 32*108
#define QW      108
#define QH      32
#define NPTS    8192
#define MCAP    3072    // per-quadrant center capacity (expected ~2048, 26 sigma)
#define KT4     54      // 64-key tiles per quadrant
#define SPLITS  8       // center-range splits for k4a (round-robin tiles)
#define NCENT   (4*MCAP)  // 12288

// LDS swizzle: row-major 64-float rows, column rotated by 4*row (keeps float4
// groups contiguous & 16B aligned; de-swizzle col = (cc + 4*ty_or_tx) & 63
// since 64*u wraps). Validated for correctness in R3.
#define SW(row, col) (((row) << 6) + ((((col) + ((row) << 2))) & 63))

// ---------------------------------------------------------------------------
// K1: feat/value linear maps as LDS-tiled GEMM + fold to [r][k][c] + inv-norm.
// grid (54, 2): y=0 -> feat (+invn), y=1 -> value. Block 256 = 256 pixels.
// Per thread: x column resident in 64 VGPRs, 64 outputs, W via scalar loads.
// Also zeroes cnt[] (y==0 blocks) so no separate memset dispatch is needed.
// ---------------------------------------------------------------------------
__global__ __launch_bounds__(256) void k1_linmaps(
    const float* __restrict__ x, const float* __restrict__ Wf, const float* __restrict__ bf,
    const float* __restrict__ Wv, const float* __restrict__ bv,
    float* __restrict__ featp, float* __restrict__ valp, float* __restrict__ invn,
    int* __restrict__ cnt)
{
    __shared__ float xs[64 * 256];   // 64 KB tile: 64 ch x 256 px
    int t = threadIdx.x;
    int isv = blockIdx.y;            // 0 = feat, 1 = value
    int pix0 = blockIdx.x * 256;

    int gid = blockIdx.x * 256 + t;  // 0..13823 covers cnt[0..12287]
    if (isv == 0 && gid < NCENT) cnt[gid] = 0;

    // cooperative coalesced load of the x tile (contiguous float4 rows)
    #pragma unroll
    for (int i = 0; i < 16; i++) {
        int f = t + 256 * i;          // float4 id in [0,16384)
        int row = f >> 6, col4 = f & 63;
        float4 v = *(const float4*)(x + (size_t)row * PIX + pix0 + col4 * 4);
        *(float4*)(xs + row * 256 + col4 * 4) = v;
    }
    __syncthreads();

    float xr[64];
    #pragma unroll
    for (int c = 0; c < 64; c++) xr[c] = xs[c * 256 + t];  // 2 lanes/bank: free

    int pix = pix0 + t;
    int h = pix / 216;
    int w = pix - h * 216;
    int r = ((h >> 5) << 1) | (w >= QW ? 1 : 0);
    int k = (h & 31) * QW + (w >= QW ? w - QW : w);

    const float* W  = isv ? Wv : Wf;
    const float* bb = isv ? bv : bf;
    float* dst = (isv ? valp : featp) + (size_t)(r * QPIX + k) * 64;

    float ss = 0.0f;
    for (int og = 0; og < 4; og++) {
        float acc[16];
        #pragma unroll
        for (int i = 0; i < 16; i++) {
            int o = og * 16 + i;          // wave-uniform
            float a = bb[o];
            #pragma unroll
            for (int c = 0; c < 64; c++) a = fmaf(W[o * 64 + c], xr[c], a);
            acc[i] = a;
            ss += a * a;
        }
        #pragma unroll
        for (int i = 0; i < 16; i += 4)
            *(float4*)(dst + og * 16 + i) =
                make_float4(acc[i], acc[i+1], acc[i+2], acc[i+3]);
    }
    if (isv == 0) invn[r * QPIX + k] = 1.0f / fmaxf(sqrtf(ss), 1e-12f);
}

// ---------------------------------------------------------------------------
// K2: order-preserving per-quadrant compaction in ONE block (1024 thr x 8 pts).
// Packed 4x16-bit quadrant counts scanned via wave shfl + wave-total scan.
// ---------------------------------------------------------------------------
__device__ __forceinline__ int point_quadrant(float px, float py) {
    // rh = 384/2 = 192 exact, rw = 1296/2 = 648 exact
    return ((py > 192.0f) ? 2 : 0) + ((px > 648.0f) ? 1 : 0);
}

__global__ __launch_bounds__(1024) void k2_compact(
    const float* __restrict__ points,
    float* __restrict__ cp, int* __restrict__ counts, int* __restrict__ slot)
{
    __shared__ unsigned long long wsum[16];
    int t = threadIdx.x;
    int lane = t & 63, w = t >> 6;
    const float2* pts = (const float2*)points;

    float2 p[8];
    int q[8];
    #pragma unroll
    for (int i = 0; i < 8; i++) p[i] = pts[t * 8 + i];

    unsigned long long loc = 0;          // 4 x 16-bit per-quadrant counts
    unsigned long long pre[8];
    #pragma unroll
    for (int i = 0; i < 8; i++) {
        q[i] = point_quadrant(p[i].x, p[i].y);
        pre[i] = loc;
        loc += 1ull << (q[i] * 16);
    }
    // wave inclusive scan
    unsigned long long incl = loc;
    #pragma unroll
    for (int d = 1; d < 64; d <<= 1) {
        unsigned long long n = __shfl_up(incl, d, 64);
        if (lane >= d) incl += n;
    }
    if (lane == 63) wsum[w] = incl;
    __syncthreads();
    if (t < 16) {
        unsigned long long v = wsum[t], inc = v;
        #pragma unroll
        for (int d = 1; d < 16; d <<= 1) {
            unsigned long long n = __shfl_up(inc, d, 64);
            if (t >= d) inc += n;
        }
        if (t == 15) {
            #pragma unroll
            for (int r = 0; r < 4; r++) counts[r] = (int)((inc >> (16 * r)) & 0xffff);
        }
        wsum[t] = inc - v;               // exclusive wave base
    }
    __syncthreads();
    unsigned long long tbase = wsum[w] + (incl - loc);   // thread-exclusive
    #pragma unroll
    for (int i = 0; i < 8; i++) {
        int r = q[i];
        int pos = (int)(((tbase + pre[i]) >> (16 * r)) & 0xffff);
        ((float2*)cp)[r * MCAP + pos] = p[i];
        slot[t * 8 + i] = r * MCAP + pos;
    }
}

// ---------------------------------------------------------------------------
// K3: bilinear gather (border clamp) of feat & value at compacted points;
// slot m == K_r is the phantom (0,0) padded row.
// ---------------------------------------------------------------------------
__global__ __launch_bounds__(256) void k3_gather(
    const float* __restrict__ featp, const float* __restrict__ valp,
    const float* __restrict__ cp, const int* __restrict__ counts,
    float* __restrict__ cn, float* __restrict__ vc)
{
    int r = blockIdx.y;
    int m = blockIdx.x * 256 + threadIdx.x;
    int K = counts[r];
    int Mr = min(K + 1, MCAP);
    if (m >= Mr) return;
    float px = 0.0f, py = 0.0f;
    if (m < K) { float2 p = ((const float2*)cp)[r * MCAP + m]; px = p.x; py = p.y; }

    float gx = (px / 1295.0f * 2.0f - 1.0f + 1.0f) * 54.0f - 0.5f;
    float gy = (py / 383.0f  * 2.0f - 1.0f + 1.0f) * 16.0f - 0.5f;
    float x0 = floorf(gx), y0 = floorf(gy);
    float wx = gx - x0, wy = gy - y0;
    int x0i = (int)fminf(fmaxf(x0,         0.0f), 107.0f);
    int x1i = (int)fminf(fmaxf(x0 + 1.0f,  0.0f), 107.0f);
    int y0i = (int)fminf(fmaxf(y0,         0.0f), 31.0f);
    int y1i = (int)fminf(fmaxf(y0 + 1.0f,  0.0f), 31.0f);
    float w00 = (1.0f - wx) * (1.0f - wy);
    float w01 = wx * (1.0f - wy);
    float w10 = (1.0f - wx) * wy;
    float w11 = wx * wy;

    size_t b00 = ((size_t)(r * QPIX + y0i * QW + x0i)) * 64;
    size_t b01 = ((size_t)(r * QPIX + y0i * QW + x1i)) * 64;
    size_t b10 = ((size_t)(r * QPIX + y1i * QW + x0i)) * 64;
    size_t b11 = ((size_t)(r * QPIX + y1i * QW + x1i)) * 64;
    size_t ob  = ((size_t)(r * MCAP + m)) * 64;

    float fr[64];
    float ss = 0.0f;
    #pragma unroll
    for (int c = 0; c < 64; c += 4) {
        float4 a  = *(const float4*)(featp + b00 + c);
        float4 b_ = *(const float4*)(featp + b01 + c);
        float4 g  = *(const float4*)(featp + b10 + c);
        float4 d  = *(const float4*)(featp + b11 + c);
        float e0 = a.x * w00 + b_.x * w01 + g.x * w10 + d.x * w11;
        float e1 = a.y * w00 + b_.y * w01 + g.y * w10 + d.y * w11;
        float e2 = a.z * w00 + b_.z * w01 + g.z * w10 + d.z * w11;
        float e3 = a.w * w00 + b_.w * w01 + g.w * w10 + d.w * w11;
        fr[c] = e0; fr[c+1] = e1; fr[c+2] = e2; fr[c+3] = e3;
        ss += e0*e0; ss += e1*e1; ss += e2*e2; ss += e3*e3;
    }
    float inv = 1.0f / fmaxf(sqrtf(ss), 1e-12f);
    #pragma unroll
    for (int c = 0; c < 64; c += 4) {
        *(float4*)(cn + ob + c) =
            make_float4(fr[c]*inv, fr[c+1]*inv, fr[c+2]*inv, fr[c+3]*inv);
    }
    #pragma unroll
    for (int c = 0; c < 64; c += 4) {
        float4 a  = *(const float4*)(valp + b00 + c);
        float4 b_ = *(const float4*)(valp + b01 + c);
        float4 g  = *(const float4*)(valp + b10 + c);
        float4 d  = *(const float4*)(valp + b11 + c);
        float4 o;
        o.x = a.x * w00 + b_.x * w01 + g.x * w10 + d.x * w11;
        o.y = a.y * w00 + b_.y * w01 + g.y * w10 + d.y * w11;
        o.z = a.z * w00 + b_.z * w01 + g.z * w10 + d.z * w11;
        o.w = a.w * w00 + b_.w * w01 + g.w * w10 + d.w * w11;
        *(float4*)(vc + ob + c) = o;
    }
}

// ---------------------------------------------------------------------------
// K4a: cosine-sim running argmax, 128 centers x 64 keys tile, 8x4 per thread.
// LDS bytes/FMA = 1.5 (vs 2.0 at 4x4); ~80 operand VGPRs + acc32 => ~110 regs.
// __launch_bounds__(256,3): 3 blocks/CU (LDS-bound at 48 KB) -> VGPR cap ~170,
// NO SPILL (R3's 8x8 at cap 128 spilled dot[] -> 6.6 GB scratch traffic).
// ---------------------------------------------------------------------------
__global__ __launch_bounds__(256, 3) void k4a_sim(
    const float* __restrict__ featp, const float* __restrict__ invn,
    const float* __restrict__ cn, const int* __restrict__ counts,
    const float* __restrict__ alpha_p, const float* __restrict__ beta_p,
    float* __restrict__ part_s, int* __restrict__ part_m)
{
    __shared__ float A[128 * 64];   // centers tile (reused for rs reduction)
    __shared__ float B[64 * 64];    // keys tile   (reused for rm reduction)

    int r     = blockIdx.z;
    int kt    = blockIdx.x;
    int split = blockIdx.y;
    int k0 = kt * 64;
    int t  = threadIdx.x;
    int tx = t & 15, ty = t >> 4;
    int K  = counts[r];
    int Mr = min(K + 1, MCAP);
    float alpha = alpha_p[0], beta = beta_p[0];

    // stage B: 64 keys x 64 ch, normalized; thread: row t>>2, quarter t&3
    {
        int row = t >> 2, qq = (t & 3) * 16;
        float inv = invn[r * QPIX + k0 + row];
        const float* src = featp + ((size_t)(r * QPIX + k0 + row)) * 64 + qq;
        #pragma unroll
        for (int i = 0; i < 16; i += 4) {
            float4 fv = *(const float4*)(src + i);
            fv.x *= inv; fv.y *= inv; fv.z *= inv; fv.w *= inv;
            *(float4*)(B + SW(row, qq + i)) = fv;
        }
    }

    float bs[4]; int bm[4];
    #pragma unroll
    for (int v = 0; v < 4; v++) { bs[v] = -INFINITY; bm[v] = INT_MAX; }

    int ntiles = (Mr + 127) >> 7;
    for (int ct = split; ct < ntiles; ct += SPLITS) {
        __syncthreads();   // prev tile's A reads done (first iter: covers B stage)
        {
            int row = t >> 1, hh = (t & 1) * 32;
            int mg = min(ct * 128 + row, MCAP - 1);
            const float* src = cn + ((size_t)(r * MCAP + mg)) * 64 + hh;
            #pragma unroll
            for (int i = 0; i < 32; i += 4)
                *(float4*)(A + SW(row, hh + i)) = *(const float4*)(src + i);
        }
        __syncthreads();

        float dot[8][4];
        #pragma unroll
        for (int u = 0; u < 8; u++)
            #pragma unroll
            for (int v = 0; v < 4; v++) dot[u][v] = 0.0f;

        #pragma unroll
        for (int cc = 0; cc < 64; cc += 4) {
            int ac = (cc + 4 * ty) & 63;   // swizzled col (64u wraps)
            int bc = (cc + 4 * tx) & 63;
            float4 av[8], bv[4];
            #pragma unroll
            for (int u = 0; u < 8; u++) av[u] = *(const float4*)(A + ((ty + 16*u) << 6) + ac);
            #pragma unroll
            for (int v = 0; v < 4; v++) bv[v] = *(const float4*)(B + ((tx + 16*v) << 6) + bc);
            #pragma unroll
            for (int u = 0; u < 8; u++) {
                #pragma unroll
                for (int v = 0; v < 4; v++) {
                    dot[u][v] = fmaf(av[u].x, bv[v].x, dot[u][v]);
                    dot[u][v] = fmaf(av[u].y, bv[v].y, dot[u][v]);
                    dot[u][v] = fmaf(av[u].z, bv[v].z, dot[u][v]);
                    dot[u][v] = fmaf(av[u].w, bv[v].w, dot[u][v]);
                }
            }
        }
        // running argmax; m ascending (u asc, ct asc); strict > keeps smallest m
        #pragma unroll
        for (int u = 0; u < 8; u++) {
            int mg = ct * 128 + ty + 16 * u;
            bool valid = mg < Mr;
            #pragma unroll
            for (int v = 0; v < 4; v++) {
                float s = fmaf(alpha, dot[u][v], beta);  // monotone w/ sigmoid
                if (valid && s > bs[v]) { bs[v] = s; bm[v] = mg; }
            }
        }
    }

    // cross-thread (ty) reduce per key; tie -> smaller m. Reuse A/B space.
    float* rs = A;          // [16][17]
    int*   rm = (int*)B;    // [16][17]
    size_t pb = ((size_t)((r * KT4 + kt) * SPLITS + split)) * 64;
    #pragma unroll
    for (int v = 0; v < 4; v++) {
        __syncthreads();
        rs[ty * 17 + tx] = bs[v]; rm[ty * 17 + tx] = bm[v];
        __syncthreads();
        for (int st = 8; st > 0; st >>= 1) {
            if (ty < st) {
                float s2 = rs[(ty + st) * 17 + tx]; int m2 = rm[(ty + st) * 17 + tx];
                if (s2 > rs[ty * 17 + tx] ||
                    (s2 == rs[ty * 17 + tx] && m2 < rm[ty * 17 + tx])) {
                    rs[ty * 17 + tx] = s2; rm[ty * 17 + tx] = m2;
                }
            }
            __syncthreads();
        }
        if (ty == 0) { part_s[pb + tx + 16 * v] = rs[tx]; part_m[pb + tx + 16 * v] = rm[tx]; }
    }
}

// ---------------------------------------------------------------------------
// K4b: per-key winner (reduce splits), sigmoid weight, count per center.
// ---------------------------------------------------------------------------
__global__ __launch_bounds__(256) void k4b_win(
    const float* __restrict__ part_s, const int* __restrict__ part_m,
    const int* __restrict__ counts,
    int* __restrict__ win_m, float* __restrict__ win_w, int* __restrict__ cnt)
{
    int g = blockIdx.x * 256 + threadIdx.x;   // 0..13823
    int r = g / 3456, kk = g - r * 3456;
    int kt = kk >> 6, j = kk & 63;
    size_t base = ((size_t)((r * KT4 + kt) * SPLITS)) * 64 + j;
    float bs = -INFINITY; int bm = INT_MAX;
    #pragma unroll
    for (int s = 0; s < SPLITS; s++) {
        float s2 = part_s[base + (size_t)s * 64];
        int   m2 = part_m[base + (size_t)s * 64];
        if (s2 > bs || (s2 == bs && m2 < bm)) { bs = s2; bm = m2; }
    }
    int K = counts[r];
    if (bm < K) {
        int cg = r * MCAP + bm;
        win_m[g] = cg;
        win_w[g] = 1.0f / (1.0f + expf(-bs));
        atomicAdd(cnt + cg, 1);
    } else {
        win_m[g] = -1;
    }
}

// ---------------------------------------------------------------------------
// K4c: exclusive scan of cnt[12288] -> offs, cursor (single block, 1024 thr)
// ---------------------------------------------------------------------------
__global__ __launch_bounds__(1024) void k4c_scan(
    const int* __restrict__ cnt, int* __restrict__ offs, int* __restrict__ cursor)
{
    __shared__ int wt[16];
    __shared__ int wbase[16];
    int t = threadIdx.x;
    int lane = t & 63, w = t >> 6;
    int base = t * 12;
    int pre[12];
    int tot = 0;
    #pragma unroll
    for (int i = 0; i < 12; i++) { pre[i] = tot; tot += cnt[base + i]; }
    int incl = tot;
    #pragma unroll
    for (int d = 1; d < 64; d <<= 1) {
        int n = __shfl_up(incl, d, 64);
        if (lane >= d) incl += n;
    }
    if (lane == 63) wt[w] = incl;
    __syncthreads();
    if (t < 16) {
        int x = wt[t], inc = x;
        #pragma unroll
        for (int d = 1; d < 16; d <<= 1) {
            int n = __shfl_up(inc, d, 64);
            if (t >= d) inc += n;
        }
        wbase[t] = inc - x;
    }
    __syncthreads();
    int texcl = wbase[w] + incl - tot;
    #pragma unroll
    for (int i = 0; i < 12; i++) {
        int o = texcl + pre[i];
        offs[base + i] = o;
        cursor[base + i] = o;
    }
}

// ---------------------------------------------------------------------------
// K4d: fill member lists (1 small atomic per key)
// ---------------------------------------------------------------------------
__global__ __launch_bounds__(256) void k4d_fill(
    const int* __restrict__ win_m, const float* __restrict__ win_w,
    int* __restrict__ cursor, int* __restrict__ memb_row, float* __restrict__ memb_w)
{
    int g = blockIdx.x * 256 + threadIdx.x;
    int cg = win_m[g];
    if (cg >= 0) {
        int pos = atomicAdd(cursor + cg, 1);
        int r = g / 3456, kk = g - r * 3456;
        memb_row[pos] = r * QPIX + kk;
        memb_w[pos] = win_w[g];
    }
}

// ---------------------------------------------------------------------------
// K4e: per-center gather-aggregate (no atomics). Wave = center, lane = channel.
// Writes every agg/denom row.
// ---------------------------------------------------------------------------
__global__ __launch_bounds__(256) void k4e_agg(
    const int* __restrict__ offs, const int* __restrict__ cnt,
    const int* __restrict__ memb_row, const float* __restrict__ memb_w,
    const float* __restrict__ valp,
    float* __restrict__ agg, float* __restrict__ denom)
{
    int ci = blockIdx.x * 4 + (threadIdx.x >> 6);
    int c  = threadIdx.x & 63;
    int start = offs[ci], len = cnt[ci];
    float acc = 0.0f, den = 0.0f;
    for (int j = 0; j < len; j++) {
        int row = memb_row[start + j];      // wave-uniform broadcast load
        float w = memb_w[start + j];
        acc = fmaf(w, valp[(size_t)row * 64 + c], acc);
        den += w;
    }
    agg[(size_t)ci * 64 + c] = acc;
    if (c == 0) denom[ci] = den;
}

// ---------------------------------------------------------------------------
// K5: per-point output + projection + transposed store [1,64,1,8192].
// Block = 16 points (4 waves x 4 pts); lane c holds Wp row c in registers;
// dot via __shfl broadcast of the wave's own o_v lanes. Full-line stores.
// ---------------------------------------------------------------------------
__global__ __launch_bounds__(256) void k5_out(
    const float* __restrict__ agg, const float* __restrict__ vc,
    const float* __restrict__ denom, const int* __restrict__ slot,
    const float* __restrict__ Wp, const float* __restrict__ bp,
    float* __restrict__ out)
{
    __shared__ float res[16][64];
    int t = threadIdx.x;
    int wv = t >> 6, c = t & 63;
    int n0 = blockIdx.x * 16;

    float4 wr[16];
    #pragma unroll
    for (int q = 0; q < 16; q++) wr[q] = ((const float4*)(Wp + c * 64))[q];
    float bpc = bp[c];

    #pragma unroll
    for (int i = 0; i < 4; i++) {
        int n = n0 + wv * 4 + i;
        int sl = slot[n];
        float d = denom[sl] + 1.0f;
        float o_v = (agg[(size_t)sl * 64 + c] + vc[(size_t)sl * 64 + c]) / d;
        unsigned long long nz = __ballot(o_v != 0.0f);   // wave == point
        float acc = bpc;
        #pragma unroll
        for (int q = 0; q < 16; q++) {
            acc = fmaf(__shfl(o_v, 4 * q + 0, 64), wr[q].x, acc);
            acc = fmaf(__shfl(o_v, 4 * q + 1, 64), wr[q].y, acc);
            acc = fmaf(__shfl(o_v, 4 * q + 2, 64), wr[q].z, acc);
            acc = fmaf(__shfl(o_v, 4 * q + 3, 64), wr[q].w, acc);
        }
        res[wv * 4 + i][c] = (nz != 0ull) ? acc : 0.0f;
    }
    __syncthreads();
    int row = t & 63, seg = t >> 6;
    float4 val = make_float4(res[seg * 4 + 0][row], res[seg * 4 + 1][row],
                             res[seg * 4 + 2][row], res[seg * 4 + 3][row]);
    *(float4*)(out + (size_t)row * NPTS + n0 + seg * 4) = val;
}

// ---------------------------------------------------------------------------
extern "C" void kernel_launch(void* const* d_in, const int* in_sizes, int n_in,
                              void* d_out, int out_size, void* d_ws, size_t ws_size,
                              hipStream_t stream) {
    const float* points = (const float*)d_in[0];
    const float* x      = (const float*)d_in[1];
    const float* Wf     = (const float*)d_in[2];
    const float* bf     = (const float*)d_in[3];
    const float* Wv     = (const float*)d_in[4];
    const float* bv     = (const float*)d_in[5];
    const float* Wp     = (const float*)d_in[6];
    const float* bp     = (const float*)d_in[7];
    const float* alpha  = (const float*)d_in[8];
    const float* beta   = (const float*)d_in[9];
    float* out = (float*)d_out;

    float* ws     = (float*)d_ws;
    float* featp  = ws;                          // 884736
    float* valp   = featp + 884736;              // 884736
    float* cn     = valp  + 884736;              // 786432 (4*MCAP*64)
    float* vc     = cn    + 786432;              // 786432
    float* agg    = vc    + 786432;              // 786432
    float* denom  = agg   + 786432;              // 12288
    float* invn   = denom + 12288;               // 13824
    float* cp     = invn  + 13824;               // 24576
    float* part_s = cp    + 24576;               // 110592 (4*54*8*64)
    int*   part_m = (int*)(part_s + 110592);     // 110592
    int*   counts = part_m + 110592;             // 16
    int*   slot   = counts + 16;                 // 8192
    int*   win_m  = slot   + 8192;               // 13824
    float* win_w  = (float*)(win_m + 13824);     // 13824
    int*   cnt    = (int*)(win_w + 13824);       // 12288
    int*   offs   = cnt    + 12288;              // 12288
    int*   cursor = offs   + 12288;              // 12288
    int*   memb_row = cursor + 12288;            // 13824
    float* memb_w = (float*)(memb_row + 13824);  // 13824
    // total ~14.6 MB of d_ws

    k1_linmaps <<<dim3(54, 2), 256, 0, stream>>>(x, Wf, bf, Wv, bv, featp, valp, invn, cnt);
    k2_compact <<<1, 1024, 0, stream>>>(points, cp, counts, slot);
    k3_gather  <<<dim3(12, 4), 256, 0, stream>>>(featp, valp, cp, counts, cn, vc);
    k4a_sim    <<<dim3(KT4, SPLITS, 4), 256, 0, stream>>>(featp, invn, cn, counts,
                                                          alpha, beta, part_s, part_m);
    k4b_win    <<<54, 256, 0, stream>>>(part_s, part_m, counts, win_m, win_w, cnt);
    k4c_scan   <<<1, 1024, 0, stream>>>(cnt, offs, cursor);
    k4d_fill   <<<54, 256, 0, stream>>>(win_m, win_w, cursor, memb_row, memb_w);
    k4e_agg    <<<NCENT / 4, 256, 0, stream>>>(offs, cnt, memb_row, memb_w, valp, agg, denom);
    k5_out     <<<NPTS / 16, 256, 0, stream>>>(agg, vc, denom, slot, Wp, bp, out);
}

// Round 5
// 1340.144 us; speedup vs baseline: 2.3021x; 2.3021x over previous
//
#include <hip/hip_runtime.h>
#include <math.h>
#include <float.h>
#include <limits.h>

// Problem constants
#define PIX     13824   // 64*216
#define QPIX    3456    // 32*108
#define QW      108
#define QH      32
#define NPTS    8192
#define MCAP    3072    // per-quadrant center capacity (expected ~2048, 26 sigma)
#define KT4     54      // 64-key tiles per quadrant
#define SPLITS  8       // center-range splits for k4a (round-robin tiles)
#define NCENT   (4*MCAP)  // 12288

// LDS swizzle: row-major 64-float rows, column rotated by 4*row (keeps float4
// groups contiguous & 16B aligned; de-swizzle col = (cc + 4*ty_or_tx) & 63
// since 64*u wraps). Correctness validated R3/R4.
#define SW(row, col) (((row) << 6) + ((((col) + ((row) << 2))) & 63))

// ---------------------------------------------------------------------------
// K1: feat/value linear maps as LDS-tiled GEMM + fold to [r][k][c] + inv-norm.
// grid (54, 2): y=0 -> feat (+invn), y=1 -> value. Block 256 = 256 pixels.
// Also zeroes cnt[] (y==0 blocks) so no separate memset dispatch is needed.
// ---------------------------------------------------------------------------
__global__ __launch_bounds__(256) void k1_linmaps(
    const float* __restrict__ x, const float* __restrict__ Wf, const float* __restrict__ bf,
    const float* __restrict__ Wv, const float* __restrict__ bv,
    float* __restrict__ featp, float* __restrict__ valp, float* __restrict__ invn,
    int* __restrict__ cnt)
{
    __shared__ float xs[64 * 256];   // 64 KB tile: 64 ch x 256 px
    int t = threadIdx.x;
    int isv = blockIdx.y;            // 0 = feat, 1 = value
    int pix0 = blockIdx.x * 256;

    int gid = blockIdx.x * 256 + t;  // 0..13823 covers cnt[0..12287]
    if (isv == 0 && gid < NCENT) cnt[gid] = 0;

    #pragma unroll
    for (int i = 0; i < 16; i++) {
        int f = t + 256 * i;          // float4 id in [0,16384)
        int row = f >> 6, col4 = f & 63;
        float4 v = *(const float4*)(x + (size_t)row * PIX + pix0 + col4 * 4);
        *(float4*)(xs + row * 256 + col4 * 4) = v;
    }
    __syncthreads();

    float xr[64];
    #pragma unroll
    for (int c = 0; c < 64; c++) xr[c] = xs[c * 256 + t];  // 2 lanes/bank: free

    int pix = pix0 + t;
    int h = pix / 216;
    int w = pix - h * 216;
    int r = ((h >> 5) << 1) | (w >= QW ? 1 : 0);
    int k = (h & 31) * QW + (w >= QW ? w - QW : w);

    const float* W  = isv ? Wv : Wf;
    const float* bb = isv ? bv : bf;
    float* dst = (isv ? valp : featp) + (size_t)(r * QPIX + k) * 64;

    float ss = 0.0f;
    for (int og = 0; og < 4; og++) {
        float acc[16];
        #pragma unroll
        for (int i = 0; i < 16; i++) {
            int o = og * 16 + i;          // wave-uniform
            float a = bb[o];
            #pragma unroll
            for (int c = 0; c < 64; c++) a = fmaf(W[o * 64 + c], xr[c], a);
            acc[i] = a;
            ss += a * a;
        }
        #pragma unroll
        for (int i = 0; i < 16; i += 4)
            *(float4*)(dst + og * 16 + i) =
                make_float4(acc[i], acc[i+1], acc[i+2], acc[i+3]);
    }
    if (isv == 0) invn[r * QPIX + k] = 1.0f / fmaxf(sqrtf(ss), 1e-12f);
}

// ---------------------------------------------------------------------------
// K2: order-preserving per-quadrant compaction in ONE block (1024 thr x 8 pts).
// ---------------------------------------------------------------------------
__device__ __forceinline__ int point_quadrant(float px, float py) {
    // rh = 384/2 = 192 exact, rw = 1296/2 = 648 exact
    return ((py > 192.0f) ? 2 : 0) + ((px > 648.0f) ? 1 : 0);
}

__global__ __launch_bounds__(1024) void k2_compact(
    const float* __restrict__ points,
    float* __restrict__ cp, int* __restrict__ counts, int* __restrict__ slot)
{
    __shared__ unsigned long long wsum[16];
    int t = threadIdx.x;
    int lane = t & 63, w = t >> 6;
    const float2* pts = (const float2*)points;

    float2 p[8];
    int q[8];
    #pragma unroll
    for (int i = 0; i < 8; i++) p[i] = pts[t * 8 + i];

    unsigned long long loc = 0;          // 4 x 16-bit per-quadrant counts
    unsigned long long pre[8];
    #pragma unroll
    for (int i = 0; i < 8; i++) {
        q[i] = point_quadrant(p[i].x, p[i].y);
        pre[i] = loc;
        loc += 1ull << (q[i] * 16);
    }
    unsigned long long incl = loc;
    #pragma unroll
    for (int d = 1; d < 64; d <<= 1) {
        unsigned long long n = __shfl_up(incl, d, 64);
        if (lane >= d) incl += n;
    }
    if (lane == 63) wsum[w] = incl;
    __syncthreads();
    if (t < 16) {
        unsigned long long v = wsum[t], inc = v;
        #pragma unroll
        for (int d = 1; d < 16; d <<= 1) {
            unsigned long long n = __shfl_up(inc, d, 64);
            if (t >= d) inc += n;
        }
        if (t == 15) {
            #pragma unroll
            for (int r = 0; r < 4; r++) counts[r] = (int)((inc >> (16 * r)) & 0xffff);
        }
        wsum[t] = inc - v;               // exclusive wave base
    }
    __syncthreads();
    unsigned long long tbase = wsum[w] + (incl - loc);   // thread-exclusive
    #pragma unroll
    for (int i = 0; i < 8; i++) {
        int r = q[i];
        int pos = (int)(((tbase + pre[i]) >> (16 * r)) & 0xffff);
        ((float2*)cp)[r * MCAP + pos] = p[i];
        slot[t * 8 + i] = r * MCAP + pos;
    }
}

// ---------------------------------------------------------------------------
// K3: bilinear gather (border clamp) of feat & value at compacted points;
// slot m == K_r is the phantom (0,0) padded row.
// ---------------------------------------------------------------------------
__global__ __launch_bounds__(256) void k3_gather(
    const float* __restrict__ featp, const float* __restrict__ valp,
    const float* __restrict__ cp, const int* __restrict__ counts,
    float* __restrict__ cn, float* __restrict__ vc)
{
    int r = blockIdx.y;
    int m = blockIdx.x * 256 + threadIdx.x;
    int K = counts[r];
    int Mr = min(K + 1, MCAP);
    if (m >= Mr) return;
    float px = 0.0f, py = 0.0f;
    if (m < K) { float2 p = ((const float2*)cp)[r * MCAP + m]; px = p.x; py = p.y; }

    float gx = (px / 1295.0f * 2.0f - 1.0f + 1.0f) * 54.0f - 0.5f;
    float gy = (py / 383.0f  * 2.0f - 1.0f + 1.0f) * 16.0f - 0.5f;
    float x0 = floorf(gx), y0 = floorf(gy);
    float wx = gx - x0, wy = gy - y0;
    int x0i = (int)fminf(fmaxf(x0,         0.0f), 107.0f);
    int x1i = (int)fminf(fmaxf(x0 + 1.0f,  0.0f), 107.0f);
    int y0i = (int)fminf(fmaxf(y0,         0.0f), 31.0f);
    int y1i = (int)fminf(fmaxf(y0 + 1.0f,  0.0f), 31.0f);
    float w00 = (1.0f - wx) * (1.0f - wy);
    float w01 = wx * (1.0f - wy);
    float w10 = (1.0f - wx) * wy;
    float w11 = wx * wy;

    size_t b00 = ((size_t)(r * QPIX + y0i * QW + x0i)) * 64;
    size_t b01 = ((size_t)(r * QPIX + y0i * QW + x1i)) * 64;
    size_t b10 = ((size_t)(r * QPIX + y1i * QW + x0i)) * 64;
    size_t b11 = ((size_t)(r * QPIX + y1i * QW + x1i)) * 64;
    size_t ob  = ((size_t)(r * MCAP + m)) * 64;

    float fr[64];
    float ss = 0.0f;
    #pragma unroll
    for (int c = 0; c < 64; c += 4) {
        float4 a  = *(const float4*)(featp + b00 + c);
        float4 b_ = *(const float4*)(featp + b01 + c);
        float4 g  = *(const float4*)(featp + b10 + c);
        float4 d  = *(const float4*)(featp + b11 + c);
        float e0 = a.x * w00 + b_.x * w01 + g.x * w10 + d.x * w11;
        float e1 = a.y * w00 + b_.y * w01 + g.y * w10 + d.y * w11;
        float e2 = a.z * w00 + b_.z * w01 + g.z * w10 + d.z * w11;
        float e3 = a.w * w00 + b_.w * w01 + g.w * w10 + d.w * w11;
        fr[c] = e0; fr[c+1] = e1; fr[c+2] = e2; fr[c+3] = e3;
        ss += e0*e0; ss += e1*e1; ss += e2*e2; ss += e3*e3;
    }
    float inv = 1.0f / fmaxf(sqrtf(ss), 1e-12f);
    #pragma unroll
    for (int c = 0; c < 64; c += 4) {
        *(float4*)(cn + ob + c) =
            make_float4(fr[c]*inv, fr[c+1]*inv, fr[c+2]*inv, fr[c+3]*inv);
    }
    #pragma unroll
    for (int c = 0; c < 64; c += 4) {
        float4 a  = *(const float4*)(valp + b00 + c);
        float4 b_ = *(const float4*)(valp + b01 + c);
        float4 g  = *(const float4*)(valp + b10 + c);
        float4 d  = *(const float4*)(valp + b11 + c);
        float4 o;
        o.x = a.x * w00 + b_.x * w01 + g.x * w10 + d.x * w11;
        o.y = a.y * w00 + b_.y * w01 + g.y * w10 + d.y * w11;
        o.z = a.z * w00 + b_.z * w01 + g.z * w10 + d.z * w11;
        o.w = a.w * w00 + b_.w * w01 + g.w * w10 + d.w * w11;
        *(float4*)(vc + ob + c) = o;
    }
}

// ---------------------------------------------------------------------------
// K4a: cosine-sim running argmax, 128 centers x 64 keys tile, 8x4 per thread.
// LDS bytes/FMA = 1.5 -> ~52us floor at the 52 TB/s ds_read_b128 ceiling.
// *** NO min-waves __launch_bounds__ arg: hipcc caps VGPRs at ~256/N for
// *** 256-thread blocks (R3: N=2 -> 128, R4: N=3 -> 84) => dot[] spills =>
// *** 6-8 GB scratch HBM traffic. Occupancy is set by LDS (48 KB -> 3/CU);
// *** uncapped allocator (~110 VGPR here) never spills.
// ---------------------------------------------------------------------------
__global__ __launch_bounds__(256) void k4a_sim(
    const float* __restrict__ featp, const float* __restrict__ invn,
    const float* __restrict__ cn, const int* __restrict__ counts,
    const float* __restrict__ alpha_p, const float* __restrict__ beta_p,
    float* __restrict__ part_s, int* __restrict__ part_m)
{
    __shared__ float A[128 * 64];   // centers tile (reused for rs reduction)
    __shared__ float B[64 * 64];    // keys tile   (reused for rm reduction)

    int r     = blockIdx.z;
    int kt    = blockIdx.x;
    int split = blockIdx.y;
    int k0 = kt * 64;
    int t  = threadIdx.x;
    int tx = t & 15, ty = t >> 4;
    int K  = counts[r];
    int Mr = min(K + 1, MCAP);
    float alpha = alpha_p[0], beta = beta_p[0];

    // stage B: 64 keys x 64 ch, normalized; thread: row t>>2, quarter t&3
    {
        int row = t >> 2, qq = (t & 3) * 16;
        float inv = invn[r * QPIX + k0 + row];
        const float* src = featp + ((size_t)(r * QPIX + k0 + row)) * 64 + qq;
        #pragma unroll
        for (int i = 0; i < 16; i += 4) {
            float4 fv = *(const float4*)(src + i);
            fv.x *= inv; fv.y *= inv; fv.z *= inv; fv.w *= inv;
            *(float4*)(B + SW(row, qq + i)) = fv;
        }
    }

    float bs[4]; int bm[4];
    #pragma unroll
    for (int v = 0; v < 4; v++) { bs[v] = -INFINITY; bm[v] = INT_MAX; }

    int ntiles = (Mr + 127) >> 7;
    for (int ct = split; ct < ntiles; ct += SPLITS) {
        __syncthreads();   // prev tile's A reads done (first iter: covers B stage)
        {
            int row = t >> 1, hh = (t & 1) * 32;
            int mg = min(ct * 128 + row, MCAP - 1);
            const float* src = cn + ((size_t)(r * MCAP + mg)) * 64 + hh;
            #pragma unroll
            for (int i = 0; i < 32; i += 4)
                *(float4*)(A + SW(row, hh + i)) = *(const float4*)(src + i);
        }
        __syncthreads();

        float dot[8][4];
        #pragma unroll
        for (int u = 0; u < 8; u++)
            #pragma unroll
            for (int v = 0; v < 4; v++) dot[u][v] = 0.0f;

        #pragma unroll
        for (int cc = 0; cc < 64; cc += 4) {
            int ac = (cc + 4 * ty) & 63;   // swizzled col (64u wraps)
            int bc = (cc + 4 * tx) & 63;
            float4 av[8], bv[4];
            #pragma unroll
            for (int u = 0; u < 8; u++) av[u] = *(const float4*)(A + ((ty + 16*u) << 6) + ac);
            #pragma unroll
            for (int v = 0; v < 4; v++) bv[v] = *(const float4*)(B + ((tx + 16*v) << 6) + bc);
            #pragma unroll
            for (int u = 0; u < 8; u++) {
                #pragma unroll
                for (int v = 0; v < 4; v++) {
                    dot[u][v] = fmaf(av[u].x, bv[v].x, dot[u][v]);
                    dot[u][v] = fmaf(av[u].y, bv[v].y, dot[u][v]);
                    dot[u][v] = fmaf(av[u].z, bv[v].z, dot[u][v]);
                    dot[u][v] = fmaf(av[u].w, bv[v].w, dot[u][v]);
                }
            }
        }
        // running argmax; m ascending (u asc, ct asc); strict > keeps smallest m
        #pragma unroll
        for (int u = 0; u < 8; u++) {
            int mg = ct * 128 + ty + 16 * u;
            bool valid = mg < Mr;
            #pragma unroll
            for (int v = 0; v < 4; v++) {
                float s = fmaf(alpha, dot[u][v], beta);  // monotone w/ sigmoid
                if (valid && s > bs[v]) { bs[v] = s; bm[v] = mg; }
            }
        }
    }

    // cross-thread (ty) reduce per key; tie -> smaller m. Reuse A/B space.
    float* rs = A;          // [16][17]
    int*   rm = (int*)B;    // [16][17]
    size_t pb = ((size_t)((r * KT4 + kt) * SPLITS + split)) * 64;
    #pragma unroll
    for (int v = 0; v < 4; v++) {
        __syncthreads();
        rs[ty * 17 + tx] = bs[v]; rm[ty * 17 + tx] = bm[v];
        __syncthreads();
        for (int st = 8; st > 0; st >>= 1) {
            if (ty < st) {
                float s2 = rs[(ty + st) * 17 + tx]; int m2 = rm[(ty + st) * 17 + tx];
                if (s2 > rs[ty * 17 + tx] ||
                    (s2 == rs[ty * 17 + tx] && m2 < rm[ty * 17 + tx])) {
                    rs[ty * 17 + tx] = s2; rm[ty * 17 + tx] = m2;
                }
            }
            __syncthreads();
        }
        if (ty == 0) { part_s[pb + tx + 16 * v] = rs[tx]; part_m[pb + tx + 16 * v] = rm[tx]; }
    }
}

// ---------------------------------------------------------------------------
// K4b: per-key winner (reduce splits), sigmoid weight, count per center.
// ---------------------------------------------------------------------------
__global__ __launch_bounds__(256) void k4b_win(
    const float* __restrict__ part_s, const int* __restrict__ part_m,
    const int* __restrict__ counts,
    int* __restrict__ win_m, float* __restrict__ win_w, int* __restrict__ cnt)
{
    int g = blockIdx.x * 256 + threadIdx.x;   // 0..13823
    int r = g / 3456, kk = g - r * 3456;
    int kt = kk >> 6, j = kk & 63;
    size_t base = ((size_t)((r * KT4 + kt) * SPLITS)) * 64 + j;
    float bs = -INFINITY; int bm = INT_MAX;
    #pragma unroll
    for (int s = 0; s < SPLITS; s++) {
        float s2 = part_s[base + (size_t)s * 64];
        int   m2 = part_m[base + (size_t)s * 64];
        if (s2 > bs || (s2 == bs && m2 < bm)) { bs = s2; bm = m2; }
    }
    int K = counts[r];
    if (bm < K) {
        int cg = r * MCAP + bm;
        win_m[g] = cg;
        win_w[g] = 1.0f / (1.0f + expf(-bs));
        atomicAdd(cnt + cg, 1);
    } else {
        win_m[g] = -1;
    }
}

// ---------------------------------------------------------------------------
// K4c: exclusive scan of cnt[12288] -> offs, cursor (single block, 1024 thr)
// ---------------------------------------------------------------------------
__global__ __launch_bounds__(1024) void k4c_scan(
    const int* __restrict__ cnt, int* __restrict__ offs, int* __restrict__ cursor)
{
    __shared__ int wt[16];
    __shared__ int wbase[16];
    int t = threadIdx.x;
    int lane = t & 63, w = t >> 6;
    int base = t * 12;
    int pre[12];
    int tot = 0;
    #pragma unroll
    for (int i = 0; i < 12; i++) { pre[i] = tot; tot += cnt[base + i]; }
    int incl = tot;
    #pragma unroll
    for (int d = 1; d < 64; d <<= 1) {
        int n = __shfl_up(incl, d, 64);
        if (lane >= d) incl += n;
    }
    if (lane == 63) wt[w] = incl;
    __syncthreads();
    if (t < 16) {
        int x = wt[t], inc = x;
        #pragma unroll
        for (int d = 1; d < 16; d <<= 1) {
            int n = __shfl_up(inc, d, 64);
            if (t >= d) inc += n;
        }
        wbase[t] = inc - x;
    }
    __syncthreads();
    int texcl = wbase[w] + incl - tot;
    #pragma unroll
    for (int i = 0; i < 12; i++) {
        int o = texcl + pre[i];
        offs[base + i] = o;
        cursor[base + i] = o;
    }
}

// ---------------------------------------------------------------------------
// K4d: fill member lists (1 small atomic per key)
// ---------------------------------------------------------------------------
__global__ __launch_bounds__(256) void k4d_fill(
    const int* __restrict__ win_m, const float* __restrict__ win_w,
    int* __restrict__ cursor, int* __restrict__ memb_row, float* __restrict__ memb_w)
{
    int g = blockIdx.x * 256 + threadIdx.x;
    int cg = win_m[g];
    if (cg >= 0) {
        int pos = atomicAdd(cursor + cg, 1);
        int r = g / 3456, kk = g - r * 3456;
        memb_row[pos] = r * QPIX + kk;
        memb_w[pos] = win_w[g];
    }
}

// ---------------------------------------------------------------------------
// K4e: per-center gather-aggregate (no atomics). Wave = center, lane = channel.
// ---------------------------------------------------------------------------
__global__ __launch_bounds__(256) void k4e_agg(
    const int* __restrict__ offs, const int* __restrict__ cnt,
    const int* __restrict__ memb_row, const float* __restrict__ memb_w,
    const float* __restrict__ valp,
    float* __restrict__ agg, float* __restrict__ denom)
{
    int ci = blockIdx.x * 4 + (threadIdx.x >> 6);
    int c  = threadIdx.x & 63;
    int start = offs[ci], len = cnt[ci];
    float acc = 0.0f, den = 0.0f;
    for (int j = 0; j < len; j++) {
        int row = memb_row[start + j];      // wave-uniform broadcast load
        float w = memb_w[start + j];
        acc = fmaf(w, valp[(size_t)row * 64 + c], acc);
        den += w;
    }
    agg[(size_t)ci * 64 + c] = acc;
    if (c == 0) denom[ci] = den;
}

// ---------------------------------------------------------------------------
// K5: per-point output + projection + transposed store [1,64,1,8192].
// ---------------------------------------------------------------------------
__global__ __launch_bounds__(256) void k5_out(
    const float* __restrict__ agg, const float* __restrict__ vc,
    const float* __restrict__ denom, const int* __restrict__ slot,
    const float* __restrict__ Wp, const float* __restrict__ bp,
    float* __restrict__ out)
{
    __shared__ float res[16][64];
    int t = threadIdx.x;
    int wv = t >> 6, c = t & 63;
    int n0 = blockIdx.x * 16;

    float4 wr[16];
    #pragma unroll
    for (int q = 0; q < 16; q++) wr[q] = ((const float4*)(Wp + c * 64))[q];
    float bpc = bp[c];

    #pragma unroll
    for (int i = 0; i < 4; i++) {
        int n = n0 + wv * 4 + i;
        int sl = slot[n];
        float d = denom[sl] + 1.0f;
        float o_v = (agg[(size_t)sl * 64 + c] + vc[(size_t)sl * 64 + c]) / d;
        unsigned long long nz = __ballot(o_v != 0.0f);   // wave == point
        float acc = bpc;
        #pragma unroll
        for (int q = 0; q < 16; q++) {
            acc = fmaf(__shfl(o_v, 4 * q + 0, 64), wr[q].x, acc);
            acc = fmaf(__shfl(o_v, 4 * q + 1, 64), wr[q].y, acc);
            acc = fmaf(__shfl(o_v, 4 * q + 2, 64), wr[q].z, acc);
            acc = fmaf(__shfl(o_v, 4 * q + 3, 64), wr[q].w, acc);
        }
        res[wv * 4 + i][c] = (nz != 0ull) ? acc : 0.0f;
    }
    __syncthreads();
    int row = t & 63, seg = t >> 6;
    float4 val = make_float4(res[seg * 4 + 0][row], res[seg * 4 + 1][row],
                             res[seg * 4 + 2][row], res[seg * 4 + 3][row]);
    *(float4*)(out + (size_t)row * NPTS + n0 + seg * 4) = val;
}

// ---------------------------------------------------------------------------
extern "C" void kernel_launch(void* const* d_in, const int* in_sizes, int n_in,
                              void* d_out, int out_size, void* d_ws, size_t ws_size,
                              hipStream_t stream) {
    const float* points = (const float*)d_in[0];
    const float* x      = (const float*)d_in[1];
    const float* Wf     = (const float*)d_in[2];
    const float* bf     = (const float*)d_in[3];
    const float* Wv     = (const float*)d_in[4];
    const float* bv     = (const float*)d_in[5];
    const float* Wp     = (const float*)d_in[6];
    const float* bp     = (const float*)d_in[7];
    const float* alpha  = (const float*)d_in[8];
    const float* beta   = (const float*)d_in[9];
    float* out = (float*)d_out;

    float* ws     = (float*)d_ws;
    float* featp  = ws;                          // 884736
    float* valp   = featp + 884736;              // 884736
    float* cn     = valp  + 884736;              // 786432 (4*MCAP*64)
    float* vc     = cn    + 786432;              // 786432
    float* agg    = vc    + 786432;              // 786432
    float* denom  = agg   + 786432;              // 12288
    float* invn   = denom + 12288;               // 13824
    float* cp     = invn  + 13824;               // 24576
    float* part_s = cp    + 24576;               // 110592 (4*54*8*64)
    int*   part_m = (int*)(part_s + 110592);     // 110592
    int*   counts = part_m + 110592;             // 16
    int*   slot   = counts + 16;                 // 8192
    int*   win_m  = slot   + 8192;               // 13824
    float* win_w  = (float*)(win_m + 13824);     // 13824
    int*   cnt    = (int*)(win_w + 13824);       // 12288
    int*   offs   = cnt    + 12288;              // 12288
    int*   cursor = offs   + 12288;              // 12288
    int*   memb_row = cursor + 12288;            // 13824
    float* memb_w = (float*)(memb_row + 13824);  // 13824
    // total ~14.6 MB of d_ws

    k1_linmaps <<<dim3(54, 2), 256, 0, stream>>>(x, Wf, bf, Wv, bv, featp, valp, invn, cnt);
    k2_compact <<<1, 1024, 0, stream>>>(points, cp, counts, slot);
    k3_gather  <<<dim3(12, 4), 256, 0, stream>>>(featp, valp, cp, counts, cn, vc);
    k4a_sim    <<<dim3(KT4, SPLITS, 4), 256, 0, stream>>>(featp, invn, cn, counts,
                                                          alpha, beta, part_s, part_m);
    k4b_win    <<<54, 256, 0, stream>>>(part_s, part_m, counts, win_m, win_w, cnt);
    k4c_scan   <<<1, 1024, 0, stream>>>(cnt, offs, cursor);
    k4d_fill   <<<54, 256, 0, stream>>>(win_m, win_w, cursor, memb_row, memb_w);
    k4e_agg    <<<NCENT / 4, 256, 0, stream>>>(offs, cnt, memb_row, memb_w, valp, agg, denom);
    k5_out     <<<NPTS / 16, 256, 0, stream>>>(agg, vc, denom, slot, Wp, bp, out);
}

// Round 6
// 327.976 us; speedup vs baseline: 9.4066x; 4.0861x over previous
//
#include <hip/hip_runtime.h>
#include <math.h>
#include <float.h>
#include <limits.h>

// Problem constants
#define PIX     13824   // 64*216
#define QPIX    3456    // 32*108
#define QW      108
#define QH      32
#define NPTS    8192
#define MCAP    3072    // per-quadrant center capacity (expected ~2048, 26 sigma)
#define KT4     54      // 64-key tiles per quadrant
#define SPLITS  8       // center-range splits for k4a
#define NCENT   (4*MCAP)  // 12288

// ---------------------------------------------------------------------------
// K1: feat/value linear maps as LDS-tiled GEMM + fold to [r][k][c] + inv-norm.
// grid (54, 2): y=0 -> feat (+invn), y=1 -> value. Block 256 = 256 pixels.
// ---------------------------------------------------------------------------
__global__ __launch_bounds__(256) void k1_linmaps(
    const float* __restrict__ x, const float* __restrict__ Wf, const float* __restrict__ bf,
    const float* __restrict__ Wv, const float* __restrict__ bv,
    float* __restrict__ featp, float* __restrict__ valp, float* __restrict__ invn)
{
    __shared__ float xs[64 * 256];   // 64 KB tile: 64 ch x 256 px
    int t = threadIdx.x;
    int isv = blockIdx.y;            // 0 = feat, 1 = value
    int pix0 = blockIdx.x * 256;

    #pragma unroll
    for (int i = 0; i < 16; i++) {
        int f = t + 256 * i;          // float4 id in [0,16384)
        int row = f >> 6, col4 = f & 63;
        float4 v = *(const float4*)(x + (size_t)row * PIX + pix0 + col4 * 4);
        *(float4*)(xs + row * 256 + col4 * 4) = v;
    }
    __syncthreads();

    float xr[64];
    #pragma unroll
    for (int c = 0; c < 64; c++) xr[c] = xs[c * 256 + t];  // 2 lanes/bank: free

    int pix = pix0 + t;
    int h = pix / 216;
    int w = pix - h * 216;
    int r = ((h >> 5) << 1) | (w >= QW ? 1 : 0);
    int k = (h & 31) * QW + (w >= QW ? w - QW : w);

    const float* W  = isv ? Wv : Wf;
    const float* bb = isv ? bv : bf;
    float* dst = (isv ? valp : featp) + (size_t)(r * QPIX + k) * 64;

    float ss = 0.0f;
    for (int og = 0; og < 4; og++) {
        float acc[16];
        #pragma unroll
        for (int i = 0; i < 16; i++) {
            int o = og * 16 + i;          // wave-uniform
            float a = bb[o];
            #pragma unroll
            for (int c = 0; c < 64; c++) a = fmaf(W[o * 64 + c], xr[c], a);
            acc[i] = a;
            ss += a * a;
        }
        #pragma unroll
        for (int i = 0; i < 16; i += 4)
            *(float4*)(dst + og * 16 + i) =
                make_float4(acc[i], acc[i+1], acc[i+2], acc[i+3]);
    }
    if (isv == 0) invn[r * QPIX + k] = 1.0f / fmaxf(sqrtf(ss), 1e-12f);
}

// ---------------------------------------------------------------------------
// K2: order-preserving per-quadrant compaction in ONE block (1024 thr x 8 pts).
// ---------------------------------------------------------------------------
__device__ __forceinline__ int point_quadrant(float px, float py) {
    // rh = 384/2 = 192 exact, rw = 1296/2 = 648 exact
    return ((py > 192.0f) ? 2 : 0) + ((px > 648.0f) ? 1 : 0);
}

__global__ __launch_bounds__(1024) void k2_compact(
    const float* __restrict__ points,
    float* __restrict__ cp, int* __restrict__ counts, int* __restrict__ slot)
{
    __shared__ unsigned long long wsum[16];
    int t = threadIdx.x;
    int lane = t & 63, w = t >> 6;
    const float2* pts = (const float2*)points;

    float2 p[8];
    int q[8];
    #pragma unroll
    for (int i = 0; i < 8; i++) p[i] = pts[t * 8 + i];

    unsigned long long loc = 0;          // 4 x 16-bit per-quadrant counts
    unsigned long long pre[8];
    #pragma unroll
    for (int i = 0; i < 8; i++) {
        q[i] = point_quadrant(p[i].x, p[i].y);
        pre[i] = loc;
        loc += 1ull << (q[i] * 16);
    }
    unsigned long long incl = loc;
    #pragma unroll
    for (int d = 1; d < 64; d <<= 1) {
        unsigned long long n = __shfl_up(incl, d, 64);
        if (lane >= d) incl += n;
    }
    if (lane == 63) wsum[w] = incl;
    __syncthreads();
    if (t < 16) {
        unsigned long long v = wsum[t], inc = v;
        #pragma unroll
        for (int d = 1; d < 16; d <<= 1) {
            unsigned long long n = __shfl_up(inc, d, 64);
            if (t >= d) inc += n;
        }
        if (t == 15) {
            #pragma unroll
            for (int r = 0; r < 4; r++) counts[r] = (int)((inc >> (16 * r)) & 0xffff);
        }
        wsum[t] = inc - v;               // exclusive wave base
    }
    __syncthreads();
    unsigned long long tbase = wsum[w] + (incl - loc);   // thread-exclusive
    #pragma unroll
    for (int i = 0; i < 8; i++) {
        int r = q[i];
        int pos = (int)(((tbase + pre[i]) >> (16 * r)) & 0xffff);
        ((float2*)cp)[r * MCAP + pos] = p[i];
        slot[t * 8 + i] = r * MCAP + pos;
    }
}

// ---------------------------------------------------------------------------
// K3: bilinear gather (border clamp) of feat & value at compacted points;
// slot m == K_r is the phantom (0,0) padded row.
// ---------------------------------------------------------------------------
__global__ __launch_bounds__(256) void k3_gather(
    const float* __restrict__ featp, const float* __restrict__ valp,
    const float* __restrict__ cp, const int* __restrict__ counts,
    float* __restrict__ cn, float* __restrict__ vc)
{
    int r = blockIdx.y;
    int m = blockIdx.x * 256 + threadIdx.x;
    int K = counts[r];
    int Mr = min(K + 1, MCAP);
    if (m >= Mr) return;
    float px = 0.0f, py = 0.0f;
    if (m < K) { float2 p = ((const float2*)cp)[r * MCAP + m]; px = p.x; py = p.y; }

    float gx = (px / 1295.0f * 2.0f - 1.0f + 1.0f) * 54.0f - 0.5f;
    float gy = (py / 383.0f  * 2.0f - 1.0f + 1.0f) * 16.0f - 0.5f;
    float x0 = floorf(gx), y0 = floorf(gy);
    float wx = gx - x0, wy = gy - y0;
    int x0i = (int)fminf(fmaxf(x0,         0.0f), 107.0f);
    int x1i = (int)fminf(fmaxf(x0 + 1.0f,  0.0f), 107.0f);
    int y0i = (int)fminf(fmaxf(y0,         0.0f), 31.0f);
    int y1i = (int)fminf(fmaxf(y0 + 1.0f,  0.0f), 31.0f);
    float w00 = (1.0f - wx) * (1.0f - wy);
    float w01 = wx * (1.0f - wy);
    float w10 = (1.0f - wx) * wy;
    float w11 = wx * wy;

    size_t b00 = ((size_t)(r * QPIX + y0i * QW + x0i)) * 64;
    size_t b01 = ((size_t)(r * QPIX + y0i * QW + x1i)) * 64;
    size_t b10 = ((size_t)(r * QPIX + y1i * QW + x0i)) * 64;
    size_t b11 = ((size_t)(r * QPIX + y1i * QW + x1i)) * 64;
    size_t ob  = ((size_t)(r * MCAP + m)) * 64;

    float fr[64];
    float ss = 0.0f;
    #pragma unroll
    for (int c = 0; c < 64; c += 4) {
        float4 a  = *(const float4*)(featp + b00 + c);
        float4 b_ = *(const float4*)(featp + b01 + c);
        float4 g  = *(const float4*)(featp + b10 + c);
        float4 d  = *(const float4*)(featp + b11 + c);
        float e0 = a.x * w00 + b_.x * w01 + g.x * w10 + d.x * w11;
        float e1 = a.y * w00 + b_.y * w01 + g.y * w10 + d.y * w11;
        float e2 = a.z * w00 + b_.z * w01 + g.z * w10 + d.z * w11;
        float e3 = a.w * w00 + b_.w * w01 + g.w * w10 + d.w * w11;
        fr[c] = e0; fr[c+1] = e1; fr[c+2] = e2; fr[c+3] = e3;
        ss += e0*e0; ss += e1*e1; ss += e2*e2; ss += e3*e3;
    }
    float inv = 1.0f / fmaxf(sqrtf(ss), 1e-12f);
    #pragma unroll
    for (int c = 0; c < 64; c += 4) {
        *(float4*)(cn + ob + c) =
            make_float4(fr[c]*inv, fr[c+1]*inv, fr[c+2]*inv, fr[c+3]*inv);
    }
    #pragma unroll
    for (int c = 0; c < 64; c += 4) {
        float4 a  = *(const float4*)(valp + b00 + c);
        float4 b_ = *(const float4*)(valp + b01 + c);
        float4 g  = *(const float4*)(valp + b10 + c);
        float4 d  = *(const float4*)(valp + b11 + c);
        float4 o;
        o.x = a.x * w00 + b_.x * w01 + g.x * w10 + d.x * w11;
        o.y = a.y * w00 + b_.y * w01 + g.y * w10 + d.y * w11;
        o.z = a.z * w00 + b_.z * w01 + g.z * w10 + d.z * w11;
        o.w = a.w * w00 + b_.w * w01 + g.w * w10 + d.w * w11;
        *(float4*)(vc + ob + c) = o;
    }
}

// ---------------------------------------------------------------------------
// K4a: cosine-sim running argmax — EXACT R2-proven structure (92 us, VGPR 68,
// zero spill). 64x64 tiles, 4x4 register tile, AS=68 padded LDS.
// *** DO NOT enlarge the register tile: 8x4 and 8x8 variants (R3/R4/R5) all
// *** spill — the fully-unrolled cc-loop makes the compiler pipeline 16
// *** iterations of LDS loads (up to 768 live values), blowing any VGPR
// *** budget (even 256) => 2-8 GB scratch HBM traffic, 13-30x slowdown.
// ---------------------------------------------------------------------------
#define AS 68
__global__ __launch_bounds__(256) void k4a_sim(
    const float* __restrict__ featp, const float* __restrict__ invn,
    const float* __restrict__ cn, const int* __restrict__ counts,
    const float* __restrict__ alpha_p, const float* __restrict__ beta_p,
    float* __restrict__ part_s, int* __restrict__ part_m)
{
    __shared__ float A[64 * AS];
    __shared__ float B[64 * AS];
    __shared__ float rs[16][17];
    __shared__ int   rm[16][17];

    int r     = blockIdx.z;
    int kt    = blockIdx.x;
    int split = blockIdx.y;
    int k0 = kt * 64;
    int t  = threadIdx.x;
    int tx = t & 15, ty = t >> 4;
    int K  = counts[r];
    int Mr = min(K + 1, MCAP);
    float alpha = alpha_p[0], beta = beta_p[0];

    int ntiles = (Mr + 63) >> 6;
    int tps = (ntiles + SPLITS - 1) / SPLITS;
    int ct0 = split * tps;
    int ct1 = min(ntiles, ct0 + tps);

    float best_s[4] = {-INFINITY, -INFINITY, -INFINITY, -INFINITY};
    int   best_m[4] = {INT_MAX, INT_MAX, INT_MAX, INT_MAX};

    if (ct0 < ct1) {
        // load B tile: 64 keys x 64 ch, normalized (xn)
        {
            int j = t >> 2, cq = (t & 3) * 16;
            float inv = invn[r * QPIX + k0 + j];
            const float* src = featp + ((size_t)(r * QPIX + k0 + j)) * 64 + cq;
            float* dst = B + j * AS + cq;
            #pragma unroll
            for (int i = 0; i < 16; i += 4) {
                float4 fv = *(const float4*)(src + i);
                fv.x *= inv; fv.y *= inv; fv.z *= inv; fv.w *= inv;
                *(float4*)(dst + i) = fv;
            }
        }
        for (int ct = ct0; ct < ct1; ct++) {
            __syncthreads();   // prev tile's A reads done (also covers B load)
            {
                int row = t >> 2, cq = (t & 3) * 16;
                int mg = min(ct * 64 + row, MCAP - 1);
                const float* src = cn + ((size_t)(r * MCAP + mg)) * 64 + cq;
                float* dst = A + row * AS + cq;
                #pragma unroll
                for (int i = 0; i < 16; i += 4)
                    *(float4*)(dst + i) = *(const float4*)(src + i);
            }
            __syncthreads();

            float dot[4][4] = {};
            #pragma unroll
            for (int cc = 0; cc < 64; cc += 4) {
                float4 av[4], bv[4];
                #pragma unroll
                for (int u = 0; u < 4; u++) av[u] = *(const float4*)(A + (ty + 16*u) * AS + cc);
                #pragma unroll
                for (int v = 0; v < 4; v++) bv[v] = *(const float4*)(B + (tx + 16*v) * AS + cc);
                #pragma unroll
                for (int u = 0; u < 4; u++) {
                    #pragma unroll
                    for (int v = 0; v < 4; v++) {
                        dot[u][v] = fmaf(av[u].x, bv[v].x, dot[u][v]);
                        dot[u][v] = fmaf(av[u].y, bv[v].y, dot[u][v]);
                        dot[u][v] = fmaf(av[u].z, bv[v].z, dot[u][v]);
                        dot[u][v] = fmaf(av[u].w, bv[v].w, dot[u][v]);
                    }
                }
            }
            // running argmax; m ascending within thread; strict > keeps
            // smallest m on exact fp32 ties (reference first-max rule)
            #pragma unroll
            for (int u = 0; u < 4; u++) {
                int mg = ct * 64 + ty + 16 * u;
                bool valid = mg < Mr;
                #pragma unroll
                for (int v = 0; v < 4; v++) {
                    float s = fmaf(alpha, dot[u][v], beta);  // monotone w/ sigmoid
                    if (valid && s > best_s[v]) { best_s[v] = s; best_m[v] = mg; }
                }
            }
        }
    }

    // cross-thread (ty) reduce per key; tie -> smaller m; store partials
    size_t pb = ((size_t)((r * KT4 + kt) * SPLITS + split)) * 64;
    #pragma unroll
    for (int v = 0; v < 4; v++) {
        __syncthreads();
        rs[ty][tx] = best_s[v]; rm[ty][tx] = best_m[v];
        __syncthreads();
        for (int st = 8; st > 0; st >>= 1) {
            if (ty < st) {
                float s2 = rs[ty + st][tx]; int m2 = rm[ty + st][tx];
                if (s2 > rs[ty][tx] || (s2 == rs[ty][tx] && m2 < rm[ty][tx])) {
                    rs[ty][tx] = s2; rm[ty][tx] = m2;
                }
            }
            __syncthreads();
        }
        if (ty == 0) { part_s[pb + tx + 16 * v] = rs[0][tx]; part_m[pb + tx + 16 * v] = rm[0][tx]; }
    }
}

// ---------------------------------------------------------------------------
// K4bcd: FUSED winner-reduce + count + scan + fill, one 1024-thread block.
// LDS cnt[12288] (48 KB) serves as counter then cursor; writes global
// offs/cnt for k4e. Replaces 3 dispatches + global memset + cnt round-trip.
// ---------------------------------------------------------------------------
__global__ __launch_bounds__(1024) void k4bcd(
    const float* __restrict__ part_s, const int* __restrict__ part_m,
    const int* __restrict__ counts,
    int* __restrict__ win_m, float* __restrict__ win_w,
    int* __restrict__ offs, int* __restrict__ cnt_g,
    int* __restrict__ memb_row, float* __restrict__ memb_w)
{
    __shared__ int lcnt[NCENT];      // 48 KB
    __shared__ int wt[16];
    __shared__ int wbase[16];
    int t = threadIdx.x;
    int lane = t & 63, w = t >> 6;

    for (int i = t; i < NCENT; i += 1024) lcnt[i] = 0;
    __syncthreads();

    // phase 1: per-key winner over splits, count members per center
    for (int g = t; g < PIX; g += 1024) {
        int r = g / 3456, kk = g - r * 3456;
        int kt = kk >> 6, j = kk & 63;
        size_t base = ((size_t)((r * KT4 + kt) * SPLITS)) * 64 + j;
        float bs = -INFINITY; int bm = INT_MAX;
        #pragma unroll
        for (int s = 0; s < SPLITS; s++) {
            float s2 = part_s[base + (size_t)s * 64];
            int   m2 = part_m[base + (size_t)s * 64];
            if (s2 > bs || (s2 == bs && m2 < bm)) { bs = s2; bm = m2; }
        }
        int K = counts[r];
        if (bm < K) {
            int cg = r * MCAP + bm;
            win_m[g] = cg;
            win_w[g] = 1.0f / (1.0f + expf(-bs));
            atomicAdd(&lcnt[cg], 1);
        } else {
            win_m[g] = -1;
        }
    }
    __syncthreads();

    // phase 2: exclusive scan of lcnt -> global offs/cnt, lcnt becomes cursor
    int base = t * 12;
    int pre[12];
    int tot = 0;
    #pragma unroll
    for (int i = 0; i < 12; i++) { pre[i] = tot; tot += lcnt[base + i]; }
    int incl = tot;
    #pragma unroll
    for (int d = 1; d < 64; d <<= 1) {
        int n = __shfl_up(incl, d, 64);
        if (lane >= d) incl += n;
    }
    if (lane == 63) wt[w] = incl;
    __syncthreads();
    if (t < 16) {
        int x = wt[t], inc = x;
        #pragma unroll
        for (int d = 1; d < 16; d <<= 1) {
            int n = __shfl_up(inc, d, 64);
            if (t >= d) inc += n;
        }
        wbase[t] = inc - x;
    }
    __syncthreads();
    int texcl = wbase[w] + incl - tot;
    int myoffs[12];
    #pragma unroll
    for (int i = 0; i < 12; i++) {
        int o = texcl + pre[i];
        myoffs[i] = o;
        offs[base + i] = o;
        cnt_g[base + i] = lcnt[base + i];
    }
    __syncthreads();   // all lcnt reads done before overwrite
    #pragma unroll
    for (int i = 0; i < 12; i++) lcnt[base + i] = myoffs[i];
    __syncthreads();

    // phase 3: fill member lists via LDS cursor atomics
    for (int g = t; g < PIX; g += 1024) {
        int cg = win_m[g];
        if (cg >= 0) {
            int pos = atomicAdd(&lcnt[cg], 1);
            int r = g / 3456, kk = g - r * 3456;
            memb_row[pos] = r * QPIX + kk;
            memb_w[pos] = win_w[g];
        }
    }
}

// ---------------------------------------------------------------------------
// K4e: per-center gather-aggregate (no atomics). Wave = center, lane = channel.
// ---------------------------------------------------------------------------
__global__ __launch_bounds__(256) void k4e_agg(
    const int* __restrict__ offs, const int* __restrict__ cnt,
    const int* __restrict__ memb_row, const float* __restrict__ memb_w,
    const float* __restrict__ valp,
    float* __restrict__ agg, float* __restrict__ denom)
{
    int ci = blockIdx.x * 4 + (threadIdx.x >> 6);
    int c  = threadIdx.x & 63;
    int start = offs[ci], len = cnt[ci];
    float acc = 0.0f, den = 0.0f;
    for (int j = 0; j < len; j++) {
        int row = memb_row[start + j];      // wave-uniform broadcast load
        float w = memb_w[start + j];
        acc = fmaf(w, valp[(size_t)row * 64 + c], acc);
        den += w;
    }
    agg[(size_t)ci * 64 + c] = acc;
    if (c == 0) denom[ci] = den;
}

// ---------------------------------------------------------------------------
// K5: per-point output + projection + transposed store [1,64,1,8192].
// ---------------------------------------------------------------------------
__global__ __launch_bounds__(256) void k5_out(
    const float* __restrict__ agg, const float* __restrict__ vc,
    const float* __restrict__ denom, const int* __restrict__ slot,
    const float* __restrict__ Wp, const float* __restrict__ bp,
    float* __restrict__ out)
{
    __shared__ float res[16][64];
    int t = threadIdx.x;
    int wv = t >> 6, c = t & 63;
    int n0 = blockIdx.x * 16;

    float4 wr[16];
    #pragma unroll
    for (int q = 0; q < 16; q++) wr[q] = ((const float4*)(Wp + c * 64))[q];
    float bpc = bp[c];

    #pragma unroll
    for (int i = 0; i < 4; i++) {
        int n = n0 + wv * 4 + i;
        int sl = slot[n];
        float d = denom[sl] + 1.0f;
        float o_v = (agg[(size_t)sl * 64 + c] + vc[(size_t)sl * 64 + c]) / d;
        unsigned long long nz = __ballot(o_v != 0.0f);   // wave == point
        float acc = bpc;
        #pragma unroll
        for (int q = 0; q < 16; q++) {
            acc = fmaf(__shfl(o_v, 4 * q + 0, 64), wr[q].x, acc);
            acc = fmaf(__shfl(o_v, 4 * q + 1, 64), wr[q].y, acc);
            acc = fmaf(__shfl(o_v, 4 * q + 2, 64), wr[q].z, acc);
            acc = fmaf(__shfl(o_v, 4 * q + 3, 64), wr[q].w, acc);
        }
        res[wv * 4 + i][c] = (nz != 0ull) ? acc : 0.0f;
    }
    __syncthreads();
    int row = t & 63, seg = t >> 6;
    float4 val = make_float4(res[seg * 4 + 0][row], res[seg * 4 + 1][row],
                             res[seg * 4 + 2][row], res[seg * 4 + 3][row]);
    *(float4*)(out + (size_t)row * NPTS + n0 + seg * 4) = val;
}

// ---------------------------------------------------------------------------
extern "C" void kernel_launch(void* const* d_in, const int* in_sizes, int n_in,
                              void* d_out, int out_size, void* d_ws, size_t ws_size,
                              hipStream_t stream) {
    const float* points = (const float*)d_in[0];
    const float* x      = (const float*)d_in[1];
    const float* Wf     = (const float*)d_in[2];
    const float* bf     = (const float*)d_in[3];
    const float* Wv     = (const float*)d_in[4];
    const float* bv     = (const float*)d_in[5];
    const float* Wp     = (const float*)d_in[6];
    const float* bp     = (const float*)d_in[7];
    const float* alpha  = (const float*)d_in[8];
    const float* beta   = (const float*)d_in[9];
    float* out = (float*)d_out;

    float* ws     = (float*)d_ws;
    float* featp  = ws;                          // 884736
    float* valp   = featp + 884736;              // 884736
    float* cn     = valp  + 884736;              // 786432 (4*MCAP*64)
    float* vc     = cn    + 786432;              // 786432
    float* agg    = vc    + 786432;              // 786432
    float* denom  = agg   + 786432;              // 12288
    float* invn   = denom + 12288;               // 13824
    float* cp     = invn  + 13824;               // 24576
    float* part_s = cp    + 24576;               // 110592 (4*54*8*64)
    int*   part_m = (int*)(part_s + 110592);     // 110592
    int*   counts = part_m + 110592;             // 16
    int*   slot   = counts + 16;                 // 8192
    int*   win_m  = slot   + 8192;               // 13824
    float* win_w  = (float*)(win_m + 13824);     // 13824
    int*   cnt    = (int*)(win_w + 13824);       // 12288
    int*   offs   = cnt    + 12288;              // 12288
    int*   memb_row = offs + 12288;              // 13824
    float* memb_w = (float*)(memb_row + 13824);  // 13824
    // total ~14.6 MB of d_ws

    k1_linmaps <<<dim3(54, 2), 256, 0, stream>>>(x, Wf, bf, Wv, bv, featp, valp, invn);
    k2_compact <<<1, 1024, 0, stream>>>(points, cp, counts, slot);
    k3_gather  <<<dim3(12, 4), 256, 0, stream>>>(featp, valp, cp, counts, cn, vc);
    k4a_sim    <<<dim3(KT4, SPLITS, 4), 256, 0, stream>>>(featp, invn, cn, counts,
                                                          alpha, beta, part_s, part_m);
    k4bcd      <<<1, 1024, 0, stream>>>(part_s, part_m, counts, win_m, win_w,
                                        offs, cnt, memb_row, memb_w);
    k4e_agg    <<<NCENT / 4, 256, 0, stream>>>(offs, cnt, memb_row, memb_w, valp, agg, denom);
    k5_out     <<<NPTS / 16, 256, 0, stream>>>(agg, vc, denom, slot, Wp, bp, out);
}